// Round 7
// baseline (230.345 us; speedup 1.0000x reference)
//
#include <hip/hip_runtime.h>
#include <math.h>

#define Bn 64
#define Tn 2048
#define NCLS 20
#define Dn 2048
#define LCSL 64
#define FSDL 32

typedef __bf16 bf16x4 __attribute__((ext_vector_type(4)));
typedef __bf16 bf16x8 __attribute__((ext_vector_type(8)));
typedef float f32x4 __attribute__((ext_vector_type(4)));

// ws float offsets (every consumed slot written each call; no atomics, no counters)
#define WS_LCS 0         // 64   lcs dp results
#define WS_FSD 64        // 64   fsd dp results
#define WS_NORM 128      // 384  feat norms
#define WS_GS 512        // 512  guide/sparse partials [128 blocks][4]
// END = 1024 floats

// block roles (single mega launch, 512 threads/block), GEMM blocks first:
//   [0,64)     LCS fused GEMM(64x64,K=2048) + normalize + DP   (1 block per b)
//   [64,128)   FSD fused GEMM(2x 32x32,K=1024 concurrent) + DP (1 block per b)
//   [128,256)  guide+sparse partial reductions
//   [256,304)  feature norms (384 rows, wave per row)
#define NBLK 304

__global__ __launch_bounds__(512) void mega_kernel(
    const float* __restrict__ lcs0, const float* __restrict__ lcs1,
    const float* __restrict__ fA0, const float* __restrict__ fA1,
    const float* __restrict__ fB1,
    const float* __restrict__ vid0, const float* __restrict__ vid1,
    const float* __restrict__ cas0, const float* __restrict__ att0,
    const float* __restrict__ cas1, const float* __restrict__ att1,
    const float* __restrict__ f0, const float* __restrict__ f1,
    const float* __restrict__ f2, const float* __restrict__ f3,
    const float* __restrict__ f4, const float* __restrict__ f5,
    float* __restrict__ ws) {
    __shared__ __align__(16) __bf16 tA[2][4096];   // 16 KB
    __shared__ __align__(16) __bf16 tB[2][4096];   // 16 KB
    __shared__ __align__(16) float S[64 * 68];     // 17.4 KB (LCS S | FSD M+G | guide red)
    __shared__ float inv[128];
    const int t = threadIdx.x;
    const int bid = blockIdx.x;
    const int w = t >> 6, lane = t & 63;
    const int quad = lane >> 4, l16 = lane & 15;

    if (bid < 64) {
        // ======== LCS fused: GEMM 64x64 K=2048 + normalize + DP ========
        const int b = bid;
        const float* c0 = lcs0 + (size_t)b * LCSL * Dn;
        const float* c1 = lcs1 + (size_t)b * LCSL * Dn;
        constexpr int KC = 32;   // 32 stages of 64 cols

        f32x4 acc[2] = {};
        float sqa[2] = {0.f, 0.f}, sqb[2] = {0.f, 0.f};
        float4 pA[2], pB[2];

        auto LOADL = [&](int st) {
            #pragma unroll
            for (int l = 0; l < 2; ++l) {
                int idx4 = l * 512 + t;            // 1024 slots = 64 rows x 16 float4
                int row = idx4 >> 4, kq4 = idx4 & 15;
                pA[l] = *(const float4*)(c0 + (size_t)row * Dn + st * 64 + kq4 * 4);
                pB[l] = *(const float4*)(c1 + (size_t)row * Dn + st * 64 + kq4 * 4);
            }
        };
        auto WRITEL = [&](int buf) {
            #pragma unroll
            for (int l = 0; l < 2; ++l) {
                int idx4 = l * 512 + t;
                int row = idx4 >> 4, kq4 = idx4 & 15;
                int c = kq4 >> 1, h = kq4 & 1;
                int pos = row * 64 + ((c ^ (row & 7)) << 3) + h * 4;
                float4 av = pA[l], bv = pB[l];
                bf16x4 a4 = {(__bf16)av.x, (__bf16)av.y, (__bf16)av.z, (__bf16)av.w};
                bf16x4 b4 = {(__bf16)bv.x, (__bf16)bv.y, (__bf16)bv.z, (__bf16)bv.w};
                *(bf16x4*)&tA[buf][pos] = a4;
                *(bf16x4*)&tB[buf][pos] = b4;
                sqa[l] += av.x * av.x + av.y * av.y + av.z * av.z + av.w * av.w;
                sqb[l] += bv.x * bv.x + bv.y * bv.y + bv.z * bv.z + bv.w * bv.w;
            }
        };

        LOADL(0);
        WRITEL(0);
        LOADL(1);
        __syncthreads();
        for (int kc = 0; kc < KC; ++kc) {
            const int cur = kc & 1;
            #pragma unroll
            for (int s = 0; s < 2; ++s) {
                int ar = (w >> 1) * 16 + l16;
                int ac_ = (s * 4 + quad) ^ (ar & 7);
                bf16x8 af = *(const bf16x8*)&tA[cur][ar * 64 + (ac_ << 3)];
                #pragma unroll
                for (int tj = 0; tj < 2; ++tj) {
                    int br = (w & 1) * 32 + tj * 16 + l16;
                    int bc = (s * 4 + quad) ^ (br & 7);
                    bf16x8 bf = *(const bf16x8*)&tB[cur][br * 64 + (bc << 3)];
                    acc[tj] = __builtin_amdgcn_mfma_f32_16x16x32_bf16(af, bf, acc[tj], 0, 0, 0);
                }
            }
            if (kc + 1 < KC) {
                WRITEL(cur ^ 1);
                if (kc + 2 < KC) LOADL(kc + 2);
                __syncthreads();
            }
        }
        // row norms: 16 lanes per row slice
        #pragma unroll
        for (int l = 0; l < 2; ++l) {
            float sa = sqa[l], sb = sqb[l];
            #pragma unroll
            for (int m = 1; m < 16; m <<= 1) {
                sa += __shfl_xor(sa, m);
                sb += __shfl_xor(sb, m);
            }
            if ((t & 15) == 0) {
                int r = l * 32 + (t >> 4);
                inv[r] = sa;
                inv[64 + r] = sb;
            }
        }
        __syncthreads();
        if (t < 128) inv[t] = 1.0f / sqrtf(inv[t]);
        __syncthreads();
        // normalized S into LDS
        #pragma unroll
        for (int tj = 0; tj < 2; ++tj)
            #pragma unroll
            for (int rg = 0; rg < 4; ++rg) {
                int row = (w >> 1) * 16 + quad * 4 + rg;
                int col = (w & 1) * 32 + tj * 16 + l16;
                S[row * 68 + col] = acc[tj][rg] * inv[row] * inv[64 + col];
            }
        __syncthreads();
        // DP (anti-diagonal wavefront, wave 0)
        if (t < 64) {
            float prev = 0.f, prevprev = 0.f;
            float sval_next = S[t * 68 + 0];
            for (int d = 2; d <= 128; ++d) {
                float s = sval_next;
                int jn = d - t - 1;
                if (jn >= 0 && jn < 64) sval_next = S[t * 68 + jn];
                float up = __shfl_up(prev, 1);
                float dg = __shfl_up(prevprev, 1);
                if (t == 0) { up = 0.f; dg = 0.f; }
                int j = d - t - 1;
                float left = prev;
                float val = (s > 0.5f) ? (dg + s) : fmaxf(up, left);
                float cur = (j >= 1 && j <= 64) ? val : 0.f;
                prevprev = prev;
                prev = cur;
            }
            if (t == 63) ws[WS_LCS + b] = prev;
        }
    } else if (bid < 128) {
        // ======== FSD fused: BOTH halves concurrent (tile rows 0-31 = M, 32-63 = G) ========
        const int b = bid - 64;
        float ps = 0.f;
        for (int c = 0; c < NCLS; ++c) ps += vid0[b * NCLS + c] * vid1[b * NCLS + c];
        const float* base1 = (ps > 0.f) ? fA1 : fB1;
        const float* c0 = fA0 + (size_t)b * FSDL * Dn;
        const float* c1 = base1 + (size_t)b * FSDL * Dn;
        const int h = w >> 2, wi = (w >> 1) & 1, wj = w & 1;  // wave -> (half, subtile)
        float* Ml = S;            // 32*36 = 1152
        float* Gl = S + 1152;     // 1152
        constexpr int KC = 16;    // 16 stages of 64 cols, both halves per stage

        f32x4 acc = {};
        float sqa[2] = {0.f, 0.f}, sqb[2] = {0.f, 0.f};
        float4 pA[2], pB[2];

        auto LOADF = [&](int st) {
            #pragma unroll
            for (int l = 0; l < 2; ++l) {
                int idx4 = l * 512 + t;            // 1024 slots = 64 tile-rows x 16 float4
                int tr = idx4 >> 4, kq4 = idx4 & 15;
                int row = tr & 31, hh = tr >> 5;   // hh: 0 = first half cols, 1 = second
                pA[l] = *(const float4*)(c0 + (size_t)row * Dn + hh * 1024 + st * 64 + kq4 * 4);
                pB[l] = *(const float4*)(c1 + (size_t)row * Dn + hh * 1024 + st * 64 + kq4 * 4);
            }
        };
        auto WRITEF = [&](int buf) {
            #pragma unroll
            for (int l = 0; l < 2; ++l) {
                int idx4 = l * 512 + t;
                int tr = idx4 >> 4, kq4 = idx4 & 15;
                int c = kq4 >> 1, hb = kq4 & 1;
                int pos = tr * 64 + ((c ^ (tr & 7)) << 3) + hb * 4;
                float4 av = pA[l], bv = pB[l];
                bf16x4 a4 = {(__bf16)av.x, (__bf16)av.y, (__bf16)av.z, (__bf16)av.w};
                bf16x4 b4 = {(__bf16)bv.x, (__bf16)bv.y, (__bf16)bv.z, (__bf16)bv.w};
                *(bf16x4*)&tA[buf][pos] = a4;
                *(bf16x4*)&tB[buf][pos] = b4;
                sqa[l] += av.x * av.x + av.y * av.y + av.z * av.z + av.w * av.w;
                sqb[l] += bv.x * bv.x + bv.y * bv.y + bv.z * bv.z + bv.w * bv.w;
            }
        };

        LOADF(0);
        WRITEF(0);
        LOADF(1);
        __syncthreads();
        for (int kc = 0; kc < KC; ++kc) {
            const int cur = kc & 1;
            #pragma unroll
            for (int s = 0; s < 2; ++s) {
                int ar = h * 32 + wi * 16 + l16;
                int ac_ = (s * 4 + quad) ^ (ar & 7);
                bf16x8 af = *(const bf16x8*)&tA[cur][ar * 64 + (ac_ << 3)];
                int br = h * 32 + wj * 16 + l16;
                int bc = (s * 4 + quad) ^ (br & 7);
                bf16x8 bf = *(const bf16x8*)&tB[cur][br * 64 + (bc << 3)];
                acc = __builtin_amdgcn_mfma_f32_16x16x32_bf16(af, bf, acc, 0, 0, 0);
            }
            if (kc + 1 < KC) {
                WRITEF(cur ^ 1);
                if (kc + 2 < KC) LOADF(kc + 2);
                __syncthreads();
            }
        }
        // norms: tile-row r = l*32 + (t>>4); inv[r] = A-norm, inv[64+r] = B-norm
        #pragma unroll
        for (int l = 0; l < 2; ++l) {
            float sa = sqa[l], sb = sqb[l];
            #pragma unroll
            for (int m = 1; m < 16; m <<= 1) {
                sa += __shfl_xor(sa, m);
                sb += __shfl_xor(sb, m);
            }
            if ((t & 15) == 0) {
                int r = l * 32 + (t >> 4);
                inv[r] = sa;
                inv[64 + r] = sb;
            }
        }
        __syncthreads();
        if (t < 128) inv[t] = 1.0f / sqrtf(inv[t]);
        __syncthreads();
        // normalize into M (half0) / G (half1)
        {
            float* T = h ? Gl : Ml;
            #pragma unroll
            for (int rg = 0; rg < 4; ++rg) {
                int row = wi * 16 + quad * 4 + rg;   // 0..31
                int col = wj * 16 + l16;             // 0..31
                T[row * 36 + col] = acc[rg] * inv[h * 32 + row] * inv[64 + h * 32 + col];
            }
        }
        __syncthreads();
        // DP
        if (t < 32) {
            float prev = 0.f, prevprev = 0.f;
            float m_next = Ml[t * 36 + 0], g_next = Gl[t * 36 + 0];
            for (int d = 2; d <= 64; ++d) {
                float m = m_next, g = g_next;
                int jn = d - t - 1;
                if (jn >= 0 && jn < 32) { m_next = Ml[t * 36 + jn]; g_next = Gl[t * 36 + jn]; }
                float up = __shfl_up(prev, 1);
                float dg = __shfl_up(prevprev, 1);
                if (t == 0) { up = 0.f; dg = 0.f; }
                int j = d - t - 1;
                float left = prev;
                float x0 = dg * 10.0f;
                float x1 = (g + up) * 10.0f;
                float x2 = (g + left) * 10.0f;
                float mx = fmaxf(x0, fmaxf(x1, x2));
                float lse = mx + __logf(__expf(x0 - mx) + __expf(x1 - mx) + __expf(x2 - mx));
                float val = m + 0.1f * lse;
                float cur = (j >= 1 && j <= 32) ? val : 0.f;
                prevprev = prev;
                prev = cur;
            }
            if (t == 31) ws[WS_FSD + b] = prev;
        }
    } else if (bid < 256) {
        // -------- guide + sparse partials --------
        const int gb = bid - 128;
        const int N = Bn * Tn;
        float g0 = 0.f, s0 = 0.f, g1 = 0.f, s1 = 0.f;
        for (int n = gb * 512 + t; n < 2 * N; n += 128 * 512) {
            int sfx = (n >= N);
            int m = sfx ? (n - N) : n;
            const float* cas = sfx ? cas1 : cas0;
            const float* att = sfx ? att1 : att0;
            float a0 = att[m * 3 + 0];
            float a1 = att[m * 3 + 1];
            float g = fabsf(1.0f - cas[m * (NCLS + 1) + NCLS] - a0);
            float s = a0 + a1;
            if (sfx) { g1 += g; s1 += s; } else { g0 += g; s0 += s; }
        }
        float* red = S;   // 4*512 = 2048 floats
        float vals[4] = {g0, s0, g1, s1};
        #pragma unroll
        for (int v = 0; v < 4; ++v) red[v * 512 + t] = vals[v];
        __syncthreads();
        for (int o = 256; o; o >>= 1) {
            if (t < o) {
                #pragma unroll
                for (int v = 0; v < 4; ++v) red[v * 512 + t] += red[v * 512 + t + o];
            }
            __syncthreads();
        }
        if (t < 4) ws[WS_GS + gb * 4 + t] = red[t * 512];
    } else {
        // -------- feature norms: 384 rows, wave per row (48 blocks x 8 waves) --------
        int R = (bid - 256) * 8 + w;
        const float* arr[6] = {f0, f1, f2, f3, f4, f5};
        const float* p = arr[R >> 6] + (size_t)(R & 63) * Dn;
        float s = 0.f;
        #pragma unroll
        for (int qd = 0; qd < 8; ++qd) {
            float4 v = *(const float4*)(p + qd * 256 + lane * 4);
            s += v.x * v.x + v.y * v.y + v.z * v.z + v.w * v.w;
        }
        for (int off = 32; off; off >>= 1) s += __shfl_down(s, off);
        if (lane == 0) ws[WS_NORM + R] = sqrtf(s);
    }
}

// wave-first block reduce over 4 waves (256 threads); 2 barriers
__device__ __forceinline__ float4 wbr4(float4 v, float4* redw, int t) {
    #pragma unroll
    for (int m = 1; m < 64; m <<= 1) {
        v.x += __shfl_xor(v.x, m);
        v.y += __shfl_xor(v.y, m);
        v.z += __shfl_xor(v.z, m);
        v.w += __shfl_xor(v.w, m);
    }
    if ((t & 63) == 0) redw[t >> 6] = v;
    __syncthreads();
    float4 r;
    r.x = redw[0].x + redw[1].x + redw[2].x + redw[3].x;
    r.y = redw[0].y + redw[1].y + redw[2].y + redw[3].y;
    r.z = redw[0].z + redw[1].z + redw[2].z + redw[3].z;
    r.w = redw[0].w + redw[1].w + redw[2].w + redw[3].w;
    __syncthreads();
    return r;
}

// ============ final combine: one block, 256 threads ============
__global__ __launch_bounds__(256) void final_kernel(
    const float* __restrict__ ai0, const float* __restrict__ ac0,
    const float* __restrict__ ab0, const float* __restrict__ vid0,
    const float* __restrict__ ai1, const float* __restrict__ ac1,
    const float* __restrict__ ab1, const float* __restrict__ vid1,
    const float* __restrict__ ws, float* __restrict__ out) {
    __shared__ float rs0[Bn], rs1[Bn], plsh[Bn];
    __shared__ __align__(16) float4 redw[4];
    int t = threadIdx.x;
    if (t < Bn) {
        float s0 = 0.f, s1 = 0.f, pp = 0.f;
        for (int c = 0; c < NCLS; ++c) {
            float a = vid0[t * NCLS + c], bl = vid1[t * NCLS + c];
            s0 += a; s1 += bl; pp += a * bl;
        }
        rs0[t] = s0;
        rs1[t] = s1;
        plsh[t] = (pp > 0.f) ? 1.f : 0.f;
    }
    __syncthreads();

    float inst0 = 0.f, cont0 = 0.f, back0 = 0.f;
    float inst1 = 0.f, cont1 = 0.f, back1 = 0.f;
    for (int idx = t; idx < Bn * (NCLS + 1); idx += 256) {
        int b = idx / (NCLS + 1), c = idx % (NCLS + 1);
        float v0 = (c < NCLS) ? vid0[b * NCLS + c] : 0.f;
        float v1 = (c < NCLS) ? vid1[b * NCLS + c] : 0.f;
        float wI0 = (c < NCLS) ? (v0 / rs0[b]) : 0.f;
        float wC0 = ((c < NCLS) ? v0 : 1.f) / (rs0[b] + 1.f);
        float wI1 = (c < NCLS) ? (v1 / rs1[b]) : 0.f;
        float wC1 = ((c < NCLS) ? v1 : 1.f) / (rs1[b] + 1.f);
        inst0 += logf(ai0[idx] + 1e-10f) * wI0;
        cont0 += logf(ac0[idx] + 1e-10f) * wC0;
        inst1 += logf(ai1[idx] + 1e-10f) * wI1;
        cont1 += logf(ac1[idx] + 1e-10f) * wC1;
        if (c == NCLS) {
            back0 += logf(ab0[idx] + 1e-10f);
            back1 += logf(ab1[idx] + 1e-10f);
        }
    }

    float g0 = 0.f, s0v = 0.f, g1 = 0.f, s1v = 0.f;
    if (t < 128) {
        float4 g = *(const float4*)&ws[WS_GS + t * 4];
        g0 = g.x; s0v = g.y; g1 = g.z; s1v = g.w;
    }

    float fv0 = 0.f, fv1 = 0.f;
    if (t < Bn) {
        const float* nm = ws + WS_NORM;
        {
            float ni = nm[0 * Bn + t], nc = nm[1 * Bn + t], nb = nm[2 * Bn + t];
            float f1 = fmaxf(50.0f - ni + nc, 0.f);
            float f2 = fmaxf(50.0f - nc + nb, 0.f);
            float f = f1 + f2 + nb;
            fv0 = f * f;
        }
        {
            float ni = nm[3 * Bn + t], nc = nm[4 * Bn + t], nb = nm[5 * Bn + t];
            float f1 = fmaxf(50.0f - ni + nc, 0.f);
            float f2 = fmaxf(50.0f - nc + nb, 0.f);
            float f = f1 + f2 + nb;
            fv1 = f * f;
        }
    }

    float posL = 0.f, negL = 0.f, posF = 0.f, negF = 0.f, pln = 0.f;
    if (t < Bn) {
        float pl = plsh[t];
        float lv = ws[WS_LCS + t];
        float fv = ws[WS_FSD + t];
        posL = lv * pl; negL = lv * (1.f - pl);
        posF = fv * pl; negF = fv * (1.f - pl);
        pln = pl;
    }

    float4 r1 = wbr4({inst0, cont0, back0, inst1}, redw, t);
    float4 r2 = wbr4({cont1, back1, g0, s0v}, redw, t);
    float4 r3 = wbr4({g1, s1v, fv0, fv1}, redw, t);
    float4 r4 = wbr4({posL, negL, posF, negF}, redw, t);
    float4 r5 = wbr4({pln, 0.f, 0.f, 0.f}, redw, t);

    if (t == 0) {
        float cls0 = -(r1.x + r1.y + r1.z) / (float)Bn;
        float cls1 = -(r1.w + r2.x + r2.y) / (float)Bn;
        float guide0 = r2.z / (float)Bn;
        float sparse0 = r2.w / (float)(Bn * 2);
        float guide1 = r3.x / (float)Bn;
        float sparse1 = r3.y / (float)(Bn * 2);
        float sFeat0 = r3.z / (float)Bn;
        float sFeat1 = r3.w / (float)Bn;
        float loss0 = cls0 + 1.0f * guide0 + 5e-05f * sFeat0 + 8e-05f * sparse0;
        float loss1 = cls1 + 1.0f * guide1 + 5e-05f * sFeat1 + 8e-05f * sparse1;
        float acm = 0.5f * (loss0 + loss1);
        float posn = r5.x;
        float negn = (float)Bn - posn;
        float lcs_loss = r4.y / (negn + 1e-10f) - r4.x / (posn + 1e-10f);
        float fsd_loss = r4.w / (negn + 1e-10f) - r4.z / (posn + 1e-10f);
        out[0] = acm + 0.01f * lcs_loss + 0.01f * fsd_loss;
    }
}

extern "C" void kernel_launch(void* const* d_in, const int* in_sizes, int n_in,
                              void* d_out, int out_size, void* d_ws, size_t ws_size,
                              hipStream_t stream) {
    (void)in_sizes; (void)n_in; (void)out_size; (void)ws_size;
    const float* ai0  = (const float*)d_in[0];
    const float* ac0  = (const float*)d_in[1];
    const float* ab0  = (const float*)d_in[2];
    const float* vid0 = (const float*)d_in[3];
    const float* att0 = (const float*)d_in[4];
    const float* fi0  = (const float*)d_in[5];
    const float* fc0  = (const float*)d_in[6];
    const float* fb0  = (const float*)d_in[7];
    const float* cas0 = (const float*)d_in[8];
    const float* lcs0 = (const float*)d_in[9];
    const float* fsdA0 = (const float*)d_in[10];
    const float* ai1  = (const float*)d_in[12];
    const float* ac1  = (const float*)d_in[13];
    const float* ab1  = (const float*)d_in[14];
    const float* vid1 = (const float*)d_in[15];
    const float* att1 = (const float*)d_in[16];
    const float* fi1  = (const float*)d_in[17];
    const float* fc1  = (const float*)d_in[18];
    const float* fb1  = (const float*)d_in[19];
    const float* cas1 = (const float*)d_in[20];
    const float* lcs1 = (const float*)d_in[21];
    const float* fsdA1 = (const float*)d_in[22];
    const float* fsdB1 = (const float*)d_in[23];

    float* ws = (float*)d_ws;

    mega_kernel<<<NBLK, 512, 0, stream>>>(
        lcs0, lcs1, fsdA0, fsdA1, fsdB1, vid0, vid1, cas0, att0, cas1, att1,
        fi0, fc0, fb0, fi1, fc1, fb1, ws);
    final_kernel<<<1, 256, 0, stream>>>(ai0, ac0, ab0, vid0, ai1, ac1, ab1, vid1,
                                        ws, (float*)d_out);
}

// Round 8
// 224.510 us; speedup vs baseline: 1.0260x; 1.0260x over previous
//
#include <hip/hip_runtime.h>
#include <math.h>

#define Bn 64
#define Tn 2048
#define NCLS 20
#define Dn 2048
#define LCSL 64
#define FSDL 32

typedef __bf16 bf16x4 __attribute__((ext_vector_type(4)));
typedef __bf16 bf16x8 __attribute__((ext_vector_type(8)));
typedef float f32x4 __attribute__((ext_vector_type(4)));

// ws float offsets (no slot read before written each call).
#define WS_LCS 0         // 64   lcs dp results
#define WS_FSD 64        // 64   fsd dp results
#define WS_NORM 128      // 384  feat norms
#define WS_GS 512        // 512  guide/sparse partials [128 blocks][4]
template <int NS>
struct WsOff {
    static constexpr size_t LSQ = 1024;                         // 64*NS*128
    static constexpr size_t FSQ = LSQ + (size_t)64 * NS * 128;  // 64*NS*64
    static constexpr size_t SPART = FSQ + (size_t)64 * NS * 64; // 64*NS*4096
    static constexpr size_t MG = SPART + (size_t)64 * NS * 4096;// 64*NS*1024
    static constexpr size_t SC = MG + (size_t)64 * NS * 1024;   // 13 scalars (raw sums)
    static constexpr size_t PL = SC + 16;                       // 64 pair labels
    static constexpr size_t END = PL + 64;
};
// SC map: 0 sInst0, 1 sCont0, 2 sBack0, 3 sInst1, 4 sCont1, 5 sBack1,
//         6 sG0, 7 sS0, 8 sG1, 9 sS1, 10 featSum0, 11 featSum1, 12 posn

#define AUXB 224   // guide(128) + norms(96) dispatched FIRST to overlap GEMM wave

// ============ mega kernel (template on NS) ============
// blocks [0,128)               : guide+sparse partial reductions
// blocks [128,224)             : feature norms (384 rows, wave per row)
// blocks [224, 224+64*NS)      : LCS partial GEMM, K=2048/NS
// blocks [.., 224+128*NS)      : FSD partial GEMM, K=2048/NS
template <int NS>
__global__ __launch_bounds__(256) void mega_kernel(
    const float* __restrict__ lcs0, const float* __restrict__ lcs1,
    const float* __restrict__ fA0, const float* __restrict__ fA1,
    const float* __restrict__ fB1,
    const float* __restrict__ vid0, const float* __restrict__ vid1,
    const float* __restrict__ cas0, const float* __restrict__ att0,
    const float* __restrict__ cas1, const float* __restrict__ att1,
    const float* __restrict__ f0, const float* __restrict__ f1,
    const float* __restrict__ f2, const float* __restrict__ f3,
    const float* __restrict__ f4, const float* __restrict__ f5,
    float* __restrict__ ws) {
    constexpr int L = (NS == 16) ? 4 : 3;
    constexpr int KC = 2048 / NS / 64;   // K-stages of 64 cols
    using O = WsOff<NS>;
    __shared__ __align__(16) __bf16 tA[2][4096];
    __shared__ __align__(16) __bf16 tB[2][4096];
    const int t = threadIdx.x;
    const int bid = blockIdx.x;
    const int w = t >> 6, lane = t & 63;
    const int quad = lane >> 4, l16 = lane & 15;

    if (bid < 128) {
        // -------- guide + sparse partials (dispatched first: long streaming) --------
        const int gb = bid;
        const int N = Bn * Tn;
        float g0 = 0.f, s0 = 0.f, g1 = 0.f, s1 = 0.f;
        for (int n = gb * 256 + t; n < 2 * N; n += 128 * 256) {
            int sfx = (n >= N);
            int m = sfx ? (n - N) : n;
            const float* cas = sfx ? cas1 : cas0;
            const float* att = sfx ? att1 : att0;
            float a0 = att[m * 3 + 0];
            float a1 = att[m * 3 + 1];
            float g = fabsf(1.0f - cas[m * (NCLS + 1) + NCLS] - a0);
            float s = a0 + a1;
            if (sfx) { g1 += g; s1 += s; } else { g0 += g; s0 += s; }
        }
        float* red = (float*)tA;   // reuse tile LDS
        float vals[4] = {g0, s0, g1, s1};
        #pragma unroll
        for (int v = 0; v < 4; ++v) red[v * 256 + t] = vals[v];
        __syncthreads();
        for (int o = 128; o; o >>= 1) {
            if (t < o) {
                #pragma unroll
                for (int v = 0; v < 4; ++v) red[v * 256 + t] += red[v * 256 + t + o];
            }
            __syncthreads();
        }
        if (t < 4) ws[WS_GS + gb * 4 + t] = red[t * 256];
    } else if (bid < AUXB) {
        // -------- feature norms: 384 rows, wave per row --------
        int R = (bid - 128) * 4 + w;
        const float* arr[6] = {f0, f1, f2, f3, f4, f5};
        const float* p = arr[R >> 6] + (size_t)(R & 63) * Dn;
        float s = 0.f;
        #pragma unroll
        for (int qd = 0; qd < 8; ++qd) {
            float4 v = *(const float4*)(p + qd * 256 + lane * 4);
            s += v.x * v.x + v.y * v.y + v.z * v.z + v.w * v.w;
        }
        for (int off = 32; off; off >>= 1) s += __shfl_down(s, off);
        if (lane == 0) ws[WS_NORM + R] = sqrtf(s);
    } else if (bid < AUXB + 64 * NS) {
        // -------- LCS partial GEMM (MFMA): out 64x64, K=2048/NS --------
        const int gb = bid - AUXB;
        const int b = gb >> L, ks = gb & (NS - 1);
        const float* c0 = lcs0 + (size_t)b * LCSL * Dn + ks * (2048 / NS);
        const float* c1 = lcs1 + (size_t)b * LCSL * Dn + ks * (2048 / NS);

        f32x4 acc[4] = {};
        float sqa[4] = {0.f, 0.f, 0.f, 0.f}, sqb[4] = {0.f, 0.f, 0.f, 0.f};
        float4 pA[4], pB[4];

        auto LOADL = [&](int st) {
            #pragma unroll
            for (int l = 0; l < 4; ++l) {
                int idx4 = l * 256 + t;            // 1024 slots = 64 rows x 16 float4
                int row = idx4 >> 4, kq4 = idx4 & 15;
                pA[l] = *(const float4*)(c0 + (size_t)row * Dn + st * 64 + kq4 * 4);
                pB[l] = *(const float4*)(c1 + (size_t)row * Dn + st * 64 + kq4 * 4);
            }
        };
        auto WRITEL = [&](int buf) {
            #pragma unroll
            for (int l = 0; l < 4; ++l) {
                int idx4 = l * 256 + t;
                int row = idx4 >> 4, kq4 = idx4 & 15;
                int c = kq4 >> 1, h = kq4 & 1;
                int pos = row * 64 + ((c ^ (row & 7)) << 3) + h * 4;
                float4 av = pA[l], bv = pB[l];
                bf16x4 a4 = {(__bf16)av.x, (__bf16)av.y, (__bf16)av.z, (__bf16)av.w};
                bf16x4 b4 = {(__bf16)bv.x, (__bf16)bv.y, (__bf16)bv.z, (__bf16)bv.w};
                *(bf16x4*)&tA[buf][pos] = a4;
                *(bf16x4*)&tB[buf][pos] = b4;
                sqa[l] += av.x * av.x + av.y * av.y + av.z * av.z + av.w * av.w;
                sqb[l] += bv.x * bv.x + bv.y * bv.y + bv.z * bv.z + bv.w * bv.w;
            }
        };

        LOADL(0);
        WRITEL(0);
        if (KC > 1) LOADL(1);
        __syncthreads();                 // buf0 ready
        for (int kc = 0; kc < KC; ++kc) {
            const int cur = kc & 1;
            #pragma unroll
            for (int s = 0; s < 2; ++s) {
                int ar = w * 16 + l16;
                int ac_ = (s * 4 + quad) ^ (ar & 7);
                bf16x8 af = *(const bf16x8*)&tA[cur][ar * 64 + (ac_ << 3)];
                #pragma unroll
                for (int tj = 0; tj < 4; ++tj) {
                    int br = tj * 16 + l16;
                    int bc = (s * 4 + quad) ^ (br & 7);
                    bf16x8 bf = *(const bf16x8*)&tB[cur][br * 64 + (bc << 3)];
                    acc[tj] = __builtin_amdgcn_mfma_f32_16x16x32_bf16(af, bf, acc[tj], 0, 0, 0);
                }
            }
            if (kc + 1 < KC) {
                WRITEL(cur ^ 1);          // stage kc+1 (safe: peers read cur or are past barrier kc-1)
                if (kc + 2 < KC) LOADL(kc + 2);
                __syncthreads();          // buf[kc+1] ready; all peers done reading cur
            }
        }
        // write partial S (f32)
        float* dst = ws + O::SPART + (size_t)(b * NS + ks) * 4096;
        #pragma unroll
        for (int tj = 0; tj < 4; ++tj)
            #pragma unroll
            for (int rg = 0; rg < 4; ++rg)
                dst[(w * 16 + quad * 4 + rg) * 64 + tj * 16 + l16] = acc[tj][rg];
        #pragma unroll
        for (int l = 0; l < 4; ++l) {
            float sa = sqa[l], sb = sqb[l];
            #pragma unroll
            for (int m = 1; m < 16; m <<= 1) {
                sa += __shfl_xor(sa, m);
                sb += __shfl_xor(sb, m);
            }
            if ((t & 15) == 0) {
                int r = l * 16 + (t >> 4);
                float* q = ws + O::LSQ + (size_t)(b * NS + ks) * 128;
                q[r] = sa;
                q[64 + r] = sb;
            }
        }
    } else {
        // -------- FSD partial GEMM (MFMA): out 32x32, K=2048/NS --------
        const int qb = bid - AUXB - 64 * NS;
        const int b = qb >> L;
        const int idx = qb & (NS - 1);
        const int half = idx >> (L - 1);
        const int ks = idx & (NS / 2 - 1);
        float ps = 0.f;
        for (int c = 0; c < NCLS; ++c) ps += vid0[b * NCLS + c] * vid1[b * NCLS + c];
        const float* base1 = (ps > 0.f) ? fA1 : fB1;
        const float* c0 = fA0 + (size_t)b * FSDL * Dn + half * 1024 + ks * (2048 / NS);
        const float* c1 = base1 + (size_t)b * FSDL * Dn + half * 1024 + ks * (2048 / NS);
        const int wi = w >> 1, wj = w & 1;

        f32x4 acc = {};
        float sqa[2] = {0.f, 0.f}, sqb[2] = {0.f, 0.f};
        float4 pA[2], pB[2];

        auto LOADF = [&](int st) {
            #pragma unroll
            for (int l = 0; l < 2; ++l) {
                int idx4 = l * 256 + t;            // 512 slots = 32 rows x 16 float4
                int row = idx4 >> 4, kq4 = idx4 & 15;
                pA[l] = *(const float4*)(c0 + (size_t)row * Dn + st * 64 + kq4 * 4);
                pB[l] = *(const float4*)(c1 + (size_t)row * Dn + st * 64 + kq4 * 4);
            }
        };
        auto WRITEF = [&](int buf) {
            #pragma unroll
            for (int l = 0; l < 2; ++l) {
                int idx4 = l * 256 + t;
                int row = idx4 >> 4, kq4 = idx4 & 15;
                int c = kq4 >> 1, h = kq4 & 1;
                int pos = row * 64 + ((c ^ (row & 7)) << 3) + h * 4;
                float4 av = pA[l], bv = pB[l];
                bf16x4 a4 = {(__bf16)av.x, (__bf16)av.y, (__bf16)av.z, (__bf16)av.w};
                bf16x4 b4 = {(__bf16)bv.x, (__bf16)bv.y, (__bf16)bv.z, (__bf16)bv.w};
                *(bf16x4*)&tA[buf][pos] = a4;
                *(bf16x4*)&tB[buf][pos] = b4;
                sqa[l] += av.x * av.x + av.y * av.y + av.z * av.z + av.w * av.w;
                sqb[l] += bv.x * bv.x + bv.y * bv.y + bv.z * bv.z + bv.w * bv.w;
            }
        };

        LOADF(0);
        WRITEF(0);
        if (KC > 1) LOADF(1);
        __syncthreads();
        for (int kc = 0; kc < KC; ++kc) {
            const int cur = kc & 1;
            #pragma unroll
            for (int s = 0; s < 2; ++s) {
                int ar = wi * 16 + l16;
                int ac_ = (s * 4 + quad) ^ (ar & 7);
                bf16x8 af = *(const bf16x8*)&tA[cur][ar * 64 + (ac_ << 3)];
                int br = wj * 16 + l16;
                int bc = (s * 4 + quad) ^ (br & 7);
                bf16x8 bf = *(const bf16x8*)&tB[cur][br * 64 + (bc << 3)];
                acc = __builtin_amdgcn_mfma_f32_16x16x32_bf16(af, bf, acc, 0, 0, 0);
            }
            if (kc + 1 < KC) {
                WRITEF(cur ^ 1);
                if (kc + 2 < KC) LOADF(kc + 2);
                __syncthreads();
            }
        }
        float* dst = ws + O::MG + (size_t)((b * 2 + half) * (NS / 2) + ks) * 1024;
        #pragma unroll
        for (int rg = 0; rg < 4; ++rg)
            dst[(wi * 16 + quad * 4 + rg) * 32 + wj * 16 + l16] = acc[rg];
        #pragma unroll
        for (int l = 0; l < 2; ++l) {
            float sa = sqa[l], sb = sqb[l];
            #pragma unroll
            for (int m = 1; m < 16; m <<= 1) {
                sa += __shfl_xor(sa, m);
                sb += __shfl_xor(sb, m);
            }
            if ((t & 15) == 0) {
                int r = l * 16 + (t >> 4);
                float* qq = ws + O::FSQ + (size_t)((b * 2 + half) * (NS / 2) + ks) * 64;
                qq[r] = sa;
                qq[32 + r] = sb;
            }
        }
    }
}

// wave-first block reduce over 4 waves (256 threads); 2 barriers
__device__ __forceinline__ float4 wbr4(float4 v, float4* redw, int t) {
    #pragma unroll
    for (int m = 1; m < 64; m <<= 1) {
        v.x += __shfl_xor(v.x, m);
        v.y += __shfl_xor(v.y, m);
        v.z += __shfl_xor(v.z, m);
        v.w += __shfl_xor(v.w, m);
    }
    if ((t & 63) == 0) redw[t >> 6] = v;
    __syncthreads();
    float4 r;
    r.x = redw[0].x + redw[1].x + redw[2].x + redw[3].x;
    r.y = redw[0].y + redw[1].y + redw[2].y + redw[3].y;
    r.z = redw[0].z + redw[1].z + redw[2].z + redw[3].z;
    r.w = redw[0].w + redw[1].w + redw[2].w + redw[3].w;
    __syncthreads();
    return r;
}

// ============ dp kernel: LCS (0..63) + FSD (64..127) + final-prep (128..131) ============
template <int NS>
__global__ __launch_bounds__(256) void dp_kernel(
    float* __restrict__ ws,
    const float* __restrict__ ai0, const float* __restrict__ ac0,
    const float* __restrict__ ab0, const float* __restrict__ vid0,
    const float* __restrict__ ai1, const float* __restrict__ ac1,
    const float* __restrict__ ab1, const float* __restrict__ vid1) {
    using O = WsOff<NS>;
    const int t = threadIdx.x;
    if (blockIdx.x < 64) {
        const int b = blockIdx.x;
        __shared__ float S[64 * 68];
        __shared__ float inv[128];
        if (t < 128) {
            float s = 0.f;
            #pragma unroll
            for (int ks = 0; ks < NS; ++ks)
                s += ws[O::LSQ + (size_t)(b * NS + ks) * 128 + t];
            inv[t] = 1.0f / sqrtf(s);
        }
        __syncthreads();
        const float* sp = ws + O::SPART + (size_t)b * NS * 4096;
        #pragma unroll
        for (int qd = 0; qd < 4; ++qd) {
            int idx4 = qd * 256 + t;
            int i = idx4 >> 4, j = (idx4 & 15) * 4;
            float4 v = {0.f, 0.f, 0.f, 0.f};
            #pragma unroll
            for (int ks = 0; ks < NS; ++ks) {
                float4 p = *(const float4*)(sp + (size_t)ks * 4096 + idx4 * 4);
                v.x += p.x; v.y += p.y; v.z += p.z; v.w += p.w;
            }
            float ri = inv[i];
            S[i * 68 + j + 0] = v.x * ri * inv[64 + j + 0];
            S[i * 68 + j + 1] = v.y * ri * inv[64 + j + 1];
            S[i * 68 + j + 2] = v.z * ri * inv[64 + j + 2];
            S[i * 68 + j + 3] = v.w * ri * inv[64 + j + 3];
        }
        __syncthreads();
        if (t < 64) {
            float prev = 0.f, prevprev = 0.f;
            float sval_next = S[t * 68 + 0];
            for (int d = 2; d <= 128; ++d) {
                float s = sval_next;
                int jn = d - t - 1;
                if (jn >= 0 && jn < 64) sval_next = S[t * 68 + jn];
                float up = __shfl_up(prev, 1);
                float dg = __shfl_up(prevprev, 1);
                if (t == 0) { up = 0.f; dg = 0.f; }
                int j = d - t - 1;
                float left = prev;
                float val = (s > 0.5f) ? (dg + s) : fmaxf(up, left);
                float cur = (j >= 1 && j <= 64) ? val : 0.f;
                prevprev = prev;
                prev = cur;
            }
            if (t == 63) ws[WS_LCS + b] = prev;
        }
    } else if (blockIdx.x < 128) {
        const int b = blockIdx.x - 64;
        __shared__ float M[32 * 36], G[32 * 36];
        __shared__ float inv[128];
        if (t < 128) {
            int half = t >> 6, sub = t & 63;
            float s = 0.f;
            #pragma unroll
            for (int ks = 0; ks < NS / 2; ++ks)
                s += ws[O::FSQ + (size_t)((b * 2 + half) * (NS / 2) + ks) * 64 + sub];
            inv[t] = 1.0f / sqrtf(s);
        }
        __syncthreads();
        {
            int idx4 = t;
            int i = idx4 >> 3, j = (idx4 & 7) * 4;
            float4 vM = {0.f, 0.f, 0.f, 0.f}, vG = {0.f, 0.f, 0.f, 0.f};
            #pragma unroll
            for (int ks = 0; ks < NS / 2; ++ks) {
                float4 pM = *(const float4*)(ws + O::MG + (size_t)((b * 2 + 0) * (NS / 2) + ks) * 1024 + idx4 * 4);
                float4 pG = *(const float4*)(ws + O::MG + (size_t)((b * 2 + 1) * (NS / 2) + ks) * 1024 + idx4 * 4);
                vM.x += pM.x; vM.y += pM.y; vM.z += pM.z; vM.w += pM.w;
                vG.x += pG.x; vG.y += pG.y; vG.z += pG.z; vG.w += pG.w;
            }
            float riM = inv[i], riG = inv[64 + i];
            M[i * 36 + j + 0] = vM.x * riM * inv[32 + j + 0];
            M[i * 36 + j + 1] = vM.y * riM * inv[32 + j + 1];
            M[i * 36 + j + 2] = vM.z * riM * inv[32 + j + 2];
            M[i * 36 + j + 3] = vM.w * riM * inv[32 + j + 3];
            G[i * 36 + j + 0] = vG.x * riG * inv[96 + j + 0];
            G[i * 36 + j + 1] = vG.y * riG * inv[96 + j + 1];
            G[i * 36 + j + 2] = vG.z * riG * inv[96 + j + 2];
            G[i * 36 + j + 3] = vG.w * riG * inv[96 + j + 3];
        }
        __syncthreads();
        if (t < 32) {
            float prev = 0.f, prevprev = 0.f;
            float m_next = M[t * 36 + 0], g_next = G[t * 36 + 0];
            for (int d = 2; d <= 64; ++d) {
                float m = m_next, g = g_next;
                int jn = d - t - 1;
                if (jn >= 0 && jn < 32) { m_next = M[t * 36 + jn]; g_next = G[t * 36 + jn]; }
                float up = __shfl_up(prev, 1);
                float dg = __shfl_up(prevprev, 1);
                if (t == 0) { up = 0.f; dg = 0.f; }
                int j = d - t - 1;
                float left = prev;
                float x0 = dg * 10.0f;
                float x1 = (g + up) * 10.0f;
                float x2 = (g + left) * 10.0f;
                float mx = fmaxf(x0, fmaxf(x1, x2));
                float lse = mx + __logf(__expf(x0 - mx) + __expf(x1 - mx) + __expf(x2 - mx));
                float val = m + 0.1f * lse;
                float cur = (j >= 1 && j <= 32) ? val : 0.f;
                prevprev = prev;
                prev = cur;
            }
            if (t == 31) ws[WS_FSD + b] = prev;
        }
    } else if (blockIdx.x == 128) {
        // -------- cls log-losses + pair labels --------
        __shared__ float rs0[Bn], rs1[Bn];
        __shared__ __align__(16) float4 redw[4];
        float plreg = 0.f;
        if (t < Bn) {
            float s0 = 0.f, s1 = 0.f, pp = 0.f;
            for (int c = 0; c < NCLS; ++c) {
                float a = vid0[t * NCLS + c], bl = vid1[t * NCLS + c];
                s0 += a; s1 += bl; pp += a * bl;
            }
            rs0[t] = s0;
            rs1[t] = s1;
            plreg = (pp > 0.f) ? 1.f : 0.f;
            ws[O::PL + t] = plreg;
        }
        __syncthreads();
        float inst0 = 0.f, cont0 = 0.f, back0 = 0.f;
        float inst1 = 0.f, cont1 = 0.f, back1 = 0.f;
        for (int idx = t; idx < Bn * (NCLS + 1); idx += 256) {
            int b = idx / (NCLS + 1), c = idx % (NCLS + 1);
            float v0 = (c < NCLS) ? vid0[b * NCLS + c] : 0.f;
            float v1 = (c < NCLS) ? vid1[b * NCLS + c] : 0.f;
            float wI0 = (c < NCLS) ? (v0 / rs0[b]) : 0.f;
            float wC0 = ((c < NCLS) ? v0 : 1.f) / (rs0[b] + 1.f);
            float wI1 = (c < NCLS) ? (v1 / rs1[b]) : 0.f;
            float wC1 = ((c < NCLS) ? v1 : 1.f) / (rs1[b] + 1.f);
            inst0 += logf(ai0[idx] + 1e-10f) * wI0;
            cont0 += logf(ac0[idx] + 1e-10f) * wC0;
            inst1 += logf(ai1[idx] + 1e-10f) * wI1;
            cont1 += logf(ac1[idx] + 1e-10f) * wC1;
            if (c == NCLS) {
                back0 += logf(ab0[idx] + 1e-10f);
                back1 += logf(ab1[idx] + 1e-10f);
            }
        }
        float4 r1 = wbr4({inst0, cont0, back0, inst1}, redw, t);
        float4 r2 = wbr4({cont1, back1, plreg, 0.f}, redw, t);
        if (t == 0) {
            ws[O::SC + 0] = r1.x; ws[O::SC + 1] = r1.y; ws[O::SC + 2] = r1.z;
            ws[O::SC + 3] = r1.w; ws[O::SC + 4] = r2.x; ws[O::SC + 5] = r2.y;
            ws[O::SC + 12] = r2.z;
        }
    } else if (blockIdx.x == 129) {
        // -------- guide/sparse combine --------
        __shared__ __align__(16) float4 redw[4];
        float4 g = {0.f, 0.f, 0.f, 0.f};
        if (t < 128) g = *(const float4*)&ws[WS_GS + t * 4];
        float4 r = wbr4(g, redw, t);
        if (t == 0) {
            ws[O::SC + 6] = r.x; ws[O::SC + 7] = r.y;
            ws[O::SC + 8] = r.z; ws[O::SC + 9] = r.w;
        }
    } else if (blockIdx.x == 130) {
        // -------- feat losses from norms --------
        __shared__ __align__(16) float4 redw[4];
        float fv0 = 0.f, fv1 = 0.f;
        if (t < Bn) {
            const float* nm = ws + WS_NORM;
            {
                float ni = nm[0 * Bn + t], nc = nm[1 * Bn + t], nb = nm[2 * Bn + t];
                float f1 = fmaxf(50.0f - ni + nc, 0.f);
                float f2 = fmaxf(50.0f - nc + nb, 0.f);
                float f = f1 + f2 + nb;
                fv0 = f * f;
            }
            {
                float ni = nm[3 * Bn + t], nc = nm[4 * Bn + t], nb = nm[5 * Bn + t];
                float f1 = fmaxf(50.0f - ni + nc, 0.f);
                float f2 = fmaxf(50.0f - nc + nb, 0.f);
                float f = f1 + f2 + nb;
                fv1 = f * f;
            }
        }
        float4 r = wbr4({fv0, fv1, 0.f, 0.f}, redw, t);
        if (t == 0) {
            ws[O::SC + 10] = r.x; ws[O::SC + 11] = r.y;
        }
    }
}

// ============ final combine: single wave, no barriers ============
template <int NS>
__global__ __launch_bounds__(64) void final_kernel(const float* __restrict__ ws,
                                                   float* __restrict__ out) {
    using O = WsOff<NS>;
    const int t = threadIdx.x;
    float pl = ws[O::PL + t];
    float lv = ws[WS_LCS + t];
    float fv = ws[WS_FSD + t];
    float4 v = {lv * pl, lv * (1.f - pl), fv * pl, fv * (1.f - pl)};
    #pragma unroll
    for (int m = 1; m < 64; m <<= 1) {
        v.x += __shfl_xor(v.x, m);
        v.y += __shfl_xor(v.y, m);
        v.z += __shfl_xor(v.z, m);
        v.w += __shfl_xor(v.w, m);
    }
    if (t == 0) {
        const float* sc = ws + O::SC;
        float cls0 = -(sc[0] + sc[1] + sc[2]) / (float)Bn;
        float cls1 = -(sc[3] + sc[4] + sc[5]) / (float)Bn;
        float guide0 = sc[6] / (float)Bn;
        float sparse0 = sc[7] / (float)(Bn * 2);
        float guide1 = sc[8] / (float)Bn;
        float sparse1 = sc[9] / (float)(Bn * 2);
        float sFeat0 = sc[10] / (float)Bn;
        float sFeat1 = sc[11] / (float)Bn;
        float loss0 = cls0 + 1.0f * guide0 + 5e-05f * sFeat0 + 8e-05f * sparse0;
        float loss1 = cls1 + 1.0f * guide1 + 5e-05f * sFeat1 + 8e-05f * sparse1;
        float acm = 0.5f * (loss0 + loss1);
        float posn = sc[12];
        float negn = (float)Bn - posn;
        float lcs_loss = v.y / (negn + 1e-10f) - v.x / (posn + 1e-10f);
        float fsd_loss = v.w / (negn + 1e-10f) - v.z / (posn + 1e-10f);
        out[0] = acm + 0.01f * lcs_loss + 0.01f * fsd_loss;
    }
}

extern "C" void kernel_launch(void* const* d_in, const int* in_sizes, int n_in,
                              void* d_out, int out_size, void* d_ws, size_t ws_size,
                              hipStream_t stream) {
    (void)in_sizes; (void)n_in; (void)out_size;
    const float* ai0  = (const float*)d_in[0];
    const float* ac0  = (const float*)d_in[1];
    const float* ab0  = (const float*)d_in[2];
    const float* vid0 = (const float*)d_in[3];
    const float* att0 = (const float*)d_in[4];
    const float* fi0  = (const float*)d_in[5];
    const float* fc0  = (const float*)d_in[6];
    const float* fb0  = (const float*)d_in[7];
    const float* cas0 = (const float*)d_in[8];
    const float* lcs0 = (const float*)d_in[9];
    const float* fsdA0 = (const float*)d_in[10];
    const float* ai1  = (const float*)d_in[12];
    const float* ac1  = (const float*)d_in[13];
    const float* ab1  = (const float*)d_in[14];
    const float* vid1 = (const float*)d_in[15];
    const float* att1 = (const float*)d_in[16];
    const float* fi1  = (const float*)d_in[17];
    const float* fc1  = (const float*)d_in[18];
    const float* fb1  = (const float*)d_in[19];
    const float* cas1 = (const float*)d_in[20];
    const float* lcs1 = (const float*)d_in[21];
    const float* fsdA1 = (const float*)d_in[22];
    const float* fsdB1 = (const float*)d_in[23];

    float* ws = (float*)d_ws;

    if (ws_size >= WsOff<16>::END * sizeof(float)) {
        mega_kernel<16><<<AUXB + 128 * 16, 256, 0, stream>>>(
            lcs0, lcs1, fsdA0, fsdA1, fsdB1, vid0, vid1, cas0, att0, cas1, att1,
            fi0, fc0, fb0, fi1, fc1, fb1, ws);
        dp_kernel<16><<<131, 256, 0, stream>>>(ws, ai0, ac0, ab0, vid0, ai1, ac1, ab1, vid1);
        final_kernel<16><<<1, 64, 0, stream>>>(ws, (float*)d_out);
    } else {
        mega_kernel<8><<<AUXB + 128 * 8, 256, 0, stream>>>(
            lcs0, lcs1, fsdA0, fsdA1, fsdB1, vid0, vid1, cas0, att0, cas1, att1,
            fi0, fc0, fb0, fi1, fc1, fb1, ws);
        dp_kernel<8><<<131, 256, 0, stream>>>(ws, ai0, ac0, ab0, vid0, ai1, ac1, ab1, vid1);
        final_kernel<8><<<1, 64, 0, stream>>>(ws, ( float*)d_out);
    }
}